// Round 13
// baseline (12796.540 us; speedup 1.0000x reference)
//
#include <hip/hip_runtime.h>
#include <cmath>

// ---------------- constants ----------------
namespace {
constexpr int BSZ = 2;
constexpr int IMGSZ = 512;
constexpr int NPATCHES = 1024;
constexpr int CH = 768;
constexpr int LAYERS = 12;
constexpr int DHEAD = 64;
constexpr int NQUERY = 100;
constexpr int NPREFIX = 5;
constexpr int NCLASS = 151;
constexpr int NBLK = 4;
constexpr int NTOK1 = NPREFIX + NPATCHES;          // 1029
constexpr int NTOK2 = NQUERY + NPREFIX + NPATCHES; // 1129
constexpr int QT = 8;
}

typedef unsigned short u16;
typedef __bf16 bf16x8 __attribute__((ext_vector_type(8)));
typedef float floatx4 __attribute__((ext_vector_type(4)));

__device__ __forceinline__ float geluf(float v) {
  return 0.5f * v * (1.0f + erff(v * 0.70710678118654752f));
}
__device__ __forceinline__ u16 f2b(float f) {
  unsigned u = __float_as_uint(f);
  u += 0x7fffu + ((u >> 16) & 1u);
  return (u16)(u >> 16);
}
__device__ __forceinline__ float b2f(u16 v) {
  return __uint_as_float(((unsigned)v) << 16);
}
__device__ __forceinline__ float b2f_lo(unsigned u) {
  return __uint_as_float(u << 16);
}
__device__ __forceinline__ float b2f_hi(unsigned u) {
  return __uint_as_float(u & 0xffff0000u);
}
__device__ __forceinline__ void gl_lds16(const u16* g, u16* l) {
  __builtin_amdgcn_global_load_lds((const __attribute__((address_space(1))) void*)g,
                                   (__attribute__((address_space(3))) void*)l, 16, 0, 0);
}
__device__ __forceinline__ float ldv(const float* p) { return *p; }
__device__ __forceinline__ float ldv(const u16* p) { return b2f(*p); }

// ---------------- fp32 -> bf16 convert (n % 4 == 0) ----------------
__global__ void k_cvt(const float* __restrict__ s, u16* __restrict__ d, int n) {
  int i = (blockIdx.x * 256 + threadIdx.x) * 4;
  if (i >= n) return;
  float4 v = *(const float4*)(s + i);
  u16 r[4] = {f2b(v.x), f2b(v.y), f2b(v.z), f2b(v.w)};
  *(uint2*)(d + i) = *(const uint2*)r;
}

// one dispatch converts all four per-layer weight tensors
__global__ __launch_bounds__(256) void k_cvt_layer(
    const float* __restrict__ qw, const float* __restrict__ pw,
    const float* __restrict__ f1, const float* __restrict__ f2,
    u16* __restrict__ dq, u16* __restrict__ dp,
    u16* __restrict__ df1, u16* __restrict__ df2) {
  constexpr size_t CC = (size_t)CH * CH;
  size_t i = ((size_t)blockIdx.x * 256 + threadIdx.x) * 8;
  if (i >= 12 * CC) return;
  const float* s; u16* d; size_t o;
  if (i < 3 * CC)      { s = qw; d = dq;  o = i; }
  else if (i < 4 * CC) { s = pw; d = dp;  o = i - 3 * CC; }
  else if (i < 8 * CC) { s = f1; d = df1; o = i - 4 * CC; }
  else                 { s = f2; d = df2; o = i - 8 * CC; }
  float4 a = *(const float4*)(s + o);
  float4 b = *(const float4*)(s + o + 4);
  u16 r[8] = {f2b(a.x), f2b(a.y), f2b(a.z), f2b(a.w),
              f2b(b.x), f2b(b.y), f2b(b.z), f2b(b.w)};
  *(uint4*)(d + o) = *(const uint4*)r;
}

// ---------------- bf16 MFMA GEMM (m97 structure) ----------------
// C[m,n] = sum_k A[m,k] * B[n,k];  A: M x K (lda), B: N x K (ldb), both bf16
// flags: 1 = gelu; 2 = upsample scatter (multi-batch); 4 = fused residual.
// zA/zB/zC: per-blockIdx.z element offsets (0 when gridDim.z == 1).
__global__ __launch_bounds__(256) void k_bgemm(
    const u16* __restrict__ A, const u16* __restrict__ B,
    const float* __restrict__ bias,
    float* __restrict__ Cf, u16* __restrict__ Cb,
    int M, int N, int K, int lda, int ldb, int ldcf, int ldcb,
    int flags, int lp2w, const float* __restrict__ lsv,
    long long zA, long long zB, long long zC) {
  __shared__ u16 As[128 * 32];
  __shared__ u16 Bs[128 * 32];
  const int tid = threadIdx.x;
  const int zz = blockIdx.z;
  A += (size_t)zz * zA;
  B += (size_t)zz * zB;
  if (Cf) Cf += (size_t)zz * zC;
  if (Cb) Cb += (size_t)zz * zC;
  const int m0 = blockIdx.y << 7, n0 = blockIdx.x << 7;
  const int wv = tid >> 6, ln = tid & 63;
  const int wm = (wv >> 1) << 6, wn = (wv & 1) << 6;
  const int fr = ln & 15, fq = ln >> 4;
  floatx4 acc[4][4];
#pragma unroll
  for (int i = 0; i < 4; i++)
#pragma unroll
    for (int j = 0; j < 4; j++) acc[i][j] = (floatx4){0.f, 0.f, 0.f, 0.f};

  const int c0 = tid, c1 = tid + 256;
  const u16* Ag0 = A + (size_t)min(m0 + (c0 >> 2), M - 1) * lda + ((c0 & 3) << 3);
  const u16* Ag1 = A + (size_t)min(m0 + (c1 >> 2), M - 1) * lda + ((c1 & 3) << 3);
  const u16* Bg0 = B + (size_t)min(n0 + (c0 >> 2), N - 1) * ldb + ((c0 & 3) << 3);
  const u16* Bg1 = B + (size_t)min(n0 + (c1 >> 2), N - 1) * ldb + ((c1 & 3) << 3);
  u16* Al0 = As + c0 * 8;
  u16* Al1 = As + c1 * 8;
  u16* Bl0 = Bs + c0 * 8;
  u16* Bl1 = Bs + c1 * 8;

  for (int k0 = 0; k0 < K; k0 += 32) {
    gl_lds16(Ag0, Al0);
    gl_lds16(Ag1, Al1);
    gl_lds16(Bg0, Bl0);
    gl_lds16(Bg1, Bl1);
    Ag0 += 32; Ag1 += 32; Bg0 += 32; Bg1 += 32;
    __syncthreads();
    bf16x8 af[4], bb[4];
#pragma unroll
    for (int mi = 0; mi < 4; mi++)
      af[mi] = *(const bf16x8*)(As + ((wm + (mi << 4) + fr) << 5) + (fq << 3));
#pragma unroll
    for (int ni = 0; ni < 4; ni++)
      bb[ni] = *(const bf16x8*)(Bs + ((wn + (ni << 4) + fr) << 5) + (fq << 3));
#pragma unroll
    for (int mi = 0; mi < 4; mi++)
#pragma unroll
      for (int ni = 0; ni < 4; ni++)
        acc[mi][ni] = __builtin_amdgcn_mfma_f32_16x16x32_bf16(af[mi], bb[ni], acc[mi][ni], 0, 0, 0);
    __syncthreads();
  }

  // C/D layout: col = lane&15 (n), row = (lane>>4)*4 + reg (m)  [m89-verified]
#pragma unroll
  for (int mi = 0; mi < 4; mi++) {
#pragma unroll
    for (int ni = 0; ni < 4; ni++) {
#pragma unroll
      for (int r = 0; r < 4; r++) {
        int m = m0 + wm + (mi << 4) + (fq << 2) + r;
        int n = n0 + wn + (ni << 4) + fr;
        if (m >= M || n >= N) continue;
        float v = acc[mi][ni][r];
        if (flags & 2) {
          int o = n % 768, dx = n / 768;
          v = geluf(v + bias[o]);
          int W = 1 << lp2w;
          int bidx = m >> (2 * lp2w);
          int mloc = m & ((1 << (2 * lp2w)) - 1);
          int y = mloc >> lp2w, x = mloc & (W - 1);
          size_t dp = ((size_t)y << (lp2w + 2)) + ((size_t)x << 1) +
                      ((size_t)(dx >> 1) << (lp2w + 1)) + (dx & 1) +
                      ((size_t)bidx << (2 * lp2w + 2));
          Cb[dp * 768 + o] = f2b(v);
        } else {
          if (bias) v += bias[n];
          if (flags & 1) v = geluf(v);
          if (flags & 4) {
            float* p = Cf + (size_t)m * ldcf + n;
            *p += lsv[n] * v;
          } else {
            if (Cf) Cf[(size_t)m * ldcf + n] = v;
            if (Cb) Cb[(size_t)m * ldcb + n] = f2b(v);
          }
        }
      }
    }
  }
}

// ---------------- row LayerNorm over 768, bf16 out (1-barrier) ----------------
template <typename T>
__global__ __launch_bounds__(256) void k_ln(const T* __restrict__ X,
                                            const float* __restrict__ w,
                                            const float* __restrict__ b,
                                            u16* __restrict__ out) {
  const int row = blockIdx.x, tid = threadIdx.x;
  const T* xr = X + (size_t)row * CH;
  float v0 = ldv(xr + tid), v1 = ldv(xr + tid + 256), v2 = ldv(xr + tid + 512);
  float s = v0 + v1 + v2;
  float q = v0 * v0 + v1 * v1 + v2 * v2;
#pragma unroll
  for (int off = 32; off; off >>= 1) {
    s += __shfl_xor(s, off);
    q += __shfl_xor(q, off);
  }
  __shared__ float sh[8];
  const int wv = tid >> 6;
  if ((tid & 63) == 0) { sh[wv] = s; sh[4 + wv] = q; }
  __syncthreads();
  s = (sh[0] + sh[1]) + (sh[2] + sh[3]);
  q = (sh[4] + sh[5]) + (sh[6] + sh[7]);
  float m = s * (1.0f / CH);
  float rstd = rsqrtf(fmaxf(q * (1.0f / CH) - m * m, 0.f) + 1e-6f);
  u16* orow = out + (size_t)row * CH;
  orow[tid]       = f2b((v0 - m) * rstd * w[tid]       + b[tid]);
  orow[tid + 256] = f2b((v1 - m) * rstd * w[tid + 256] + b[tid + 256]);
  orow[tid + 512] = f2b((v2 - m) * rstd * w[tid + 512] + b[tid + 512]);
}

// predict LN: routes query rows -> outq (contiguous 2x100), patch rows -> outp
// (contiguous per batch 2x1024); prefix rows skipped (unused downstream).
__global__ __launch_bounds__(256) void k_lnp(const float* __restrict__ X,
                                             const float* __restrict__ w,
                                             const float* __restrict__ b,
                                             u16* __restrict__ outq,
                                             u16* __restrict__ outp) {
  const int row = blockIdx.x, tid = threadIdx.x;
  const int bb = row / NTOK2, n = row - bb * NTOK2;
  u16* orow;
  if (n < NQUERY) orow = outq + (size_t)(bb * NQUERY + n) * CH;
  else if (n >= NQUERY + NPREFIX)
    orow = outp + (size_t)(bb * NPATCHES + (n - NQUERY - NPREFIX)) * CH;
  else return;
  const float* xr = X + (size_t)row * CH;
  float v0 = ldv(xr + tid), v1 = ldv(xr + tid + 256), v2 = ldv(xr + tid + 512);
  float s = v0 + v1 + v2;
  float q = v0 * v0 + v1 * v1 + v2 * v2;
#pragma unroll
  for (int off = 32; off; off >>= 1) {
    s += __shfl_xor(s, off);
    q += __shfl_xor(q, off);
  }
  __shared__ float sh[8];
  const int wv = tid >> 6;
  if ((tid & 63) == 0) { sh[wv] = s; sh[4 + wv] = q; }
  __syncthreads();
  s = (sh[0] + sh[1]) + (sh[2] + sh[3]);
  q = (sh[4] + sh[5]) + (sh[6] + sh[7]);
  float m = s * (1.0f / CH);
  float rstd = rsqrtf(fmaxf(q * (1.0f / CH) - m * m, 0.f) + 1e-6f);
  orow[tid]       = f2b((v0 - m) * rstd * w[tid]       + b[tid]);
  orow[tid + 256] = f2b((v1 - m) * rstd * w[tid + 256] + b[tid + 256]);
  orow[tid + 512] = f2b((v2 - m) * rstd * w[tid + 512] + b[tid + 512]);
}

// ---------------- fused depthwise 3x3 conv + LayerNorm (multi-batch) ---------
__global__ __launch_bounds__(256) void k_dwln(const u16* __restrict__ in,
                                              const float* __restrict__ w9,
                                              const float* __restrict__ lw,
                                              const float* __restrict__ lb,
                                              u16* __restrict__ out, int H, int W) {
  const int HW = H * W;
  int pix = blockIdx.x;
  const int bo = pix / HW;
  pix -= bo * HW;
  in += (size_t)bo * HW * CH;
  out += (size_t)bo * HW * CH;
  const int tid = threadIdx.x;
  const int x = pix % W, y = pix / W;
  float acc[3];
#pragma unroll
  for (int j = 0; j < 3; j++) {
    const int c = tid + (j << 8);
    const float* wp = w9 + c * 9;
    float sacc = 0.f;
#pragma unroll
    for (int ky = 0; ky < 3; ky++) {
      int yy = y + ky - 1;
      if (yy < 0 || yy >= H) continue;
#pragma unroll
      for (int kx = 0; kx < 3; kx++) {
        int xx = x + kx - 1;
        if (xx < 0 || xx >= W) continue;
        sacc = fmaf(wp[ky * 3 + kx], b2f(in[((size_t)yy * W + xx) * CH + c]), sacc);
      }
    }
    acc[j] = sacc;
  }
  float s = acc[0] + acc[1] + acc[2];
  float q = acc[0] * acc[0] + acc[1] * acc[1] + acc[2] * acc[2];
#pragma unroll
  for (int off = 32; off; off >>= 1) {
    s += __shfl_xor(s, off);
    q += __shfl_xor(q, off);
  }
  __shared__ float sh[8];
  const int wv = tid >> 6;
  if ((tid & 63) == 0) { sh[wv] = s; sh[4 + wv] = q; }
  __syncthreads();
  s = (sh[0] + sh[1]) + (sh[2] + sh[3]);
  q = (sh[4] + sh[5]) + (sh[6] + sh[7]);
  float m = s * (1.0f / CH);
  float rstd = rsqrtf(fmaxf(q * (1.0f / CH) - m * m, 0.f) + 1e-6f);
  u16* orow = out + (size_t)pix * CH;
#pragma unroll
  for (int j = 0; j < 3; j++) {
    const int c = tid + (j << 8);
    orow[c] = f2b((acc[j] - m) * rstd * lw[c] + lb[c]);
  }
}

// ---------------- fused attention (bf16 in/out, fp32 math) ----------------
// R12 structure (QT=8, 4 blocks/CU, K double-buffered, srow swizzled) plus:
// first 48 Q floats of row rg hoisted from LDS into registers (values are
// bit-identical; the qs reads were loop-invariant). Cuts QK-phase LDS reads
// 32 -> 20 per chunk. FMA order per chain unchanged -> bit-identical output.
#define AVROT(VV, NN, J)                                       \
  do {                                                         \
    float4 pa = *(const float4*)&srow[(NN)][0];                \
    float4 pb = *(const float4*)&srow[(NN)][4];                \
    oacc[(0 - (J)) & 7] = fmaf(pa.x, (VV), oacc[(0 - (J)) & 7]); \
    oacc[(1 - (J)) & 7] = fmaf(pa.y, (VV), oacc[(1 - (J)) & 7]); \
    oacc[(2 - (J)) & 7] = fmaf(pa.z, (VV), oacc[(2 - (J)) & 7]); \
    oacc[(3 - (J)) & 7] = fmaf(pa.w, (VV), oacc[(3 - (J)) & 7]); \
    oacc[(4 - (J)) & 7] = fmaf(pb.x, (VV), oacc[(4 - (J)) & 7]); \
    oacc[(5 - (J)) & 7] = fmaf(pb.y, (VV), oacc[(5 - (J)) & 7]); \
    oacc[(6 - (J)) & 7] = fmaf(pb.z, (VV), oacc[(6 - (J)) & 7]); \
    oacc[(7 - (J)) & 7] = fmaf(pb.w, (VV), oacc[(7 - (J)) & 7]); \
  } while (0)

__global__ __launch_bounds__(256, 4) void k_attn(const u16* __restrict__ qkv,
                                                 u16* __restrict__ out,
                                                 const unsigned char* __restrict__ qm,
                                                 int Ntok) {
  const int b = blockIdx.z, h = blockIdx.y, q0 = blockIdx.x * QT;
  const int tid = threadIdx.x;
  __shared__ float qs[QT][DHEAD];
  __shared__ float srow[1152][QT];   // [token][col] with rotation swizzle
  __shared__ float inv[QT];

  for (int idx = tid; idx < QT * DHEAD; idx += 256) {
    int r = idx >> 6, d = idx & 63;
    float v = 0.f;
    if (q0 + r < Ntok) v = b2f(qkv[(size_t)(b * Ntok + q0 + r) * (3 * CH) + h * DHEAD + d]) * 0.125f;
    qs[r][d] = v;
  }
  __syncthreads();

  const int jj = tid & 63, rg = tid >> 6;
  const u16* kbase = qkv + (size_t)b * Ntok * (3 * CH) + CH + h * DHEAD;

  // hoist qs[rg][0..47] into registers (loop-invariant; unrolled static idx)
  float qA[48];
#pragma unroll
  for (int i = 0; i < 12; i++)
    *(float4*)&qA[i * 4] = *(const float4*)&qs[rg][i * 4];

  uint4 cur[8], nxt[8];
  {
    const u16* kp = kbase + (size_t)min(jj, Ntok - 1) * (3 * CH);
#pragma unroll
    for (int i = 0; i < 8; i++) cur[i] = *(const uint4*)(kp + i * 8);
  }
  const int ksw = (jj >> 2) & 7;  // == ((nb+jj)>>2)&7 since nb % 64 == 0
  for (int nb = 0; nb < Ntok; nb += 64) {
    const bool more = (nb + 64 < Ntok);
    if (more) {
      const u16* np = kbase + (size_t)min(nb + 64 + jj, Ntok - 1) * (3 * CH);
#pragma unroll
      for (int i = 0; i < 8; i++) nxt[i] = *(const uint4*)(np + i * 8);
    }
    const int n = nb + jj;
    if (n < Ntok) {
      float a0 = 0.f, a1 = 0.f;
#pragma unroll
      for (int i = 0; i < 8; i++) {
        const int d = i << 3;
        float k0 = b2f_lo(cur[i].x), k1 = b2f_hi(cur[i].x);
        float k2 = b2f_lo(cur[i].y), k3 = b2f_hi(cur[i].y);
        float k4 = b2f_lo(cur[i].z), k5 = b2f_hi(cur[i].z);
        float k6 = b2f_lo(cur[i].w), k7 = b2f_hi(cur[i].w);
        float4 qa0, qa1;
        if (i < 6) {
          qa0 = *(const float4*)&qA[d];
          qa1 = *(const float4*)&qA[d + 4];
        } else {
          qa0 = *(const float4*)&qs[rg][d];
          qa1 = *(const float4*)&qs[rg][d + 4];
        }
        float4 qb0 = *(const float4*)&qs[rg + 4][d];
        float4 qb1 = *(const float4*)&qs[rg + 4][d + 4];
        a0 = fmaf(k0, qa0.x, a0); a0 = fmaf(k1, qa0.y, a0);
        a0 = fmaf(k2, qa0.z, a0); a0 = fmaf(k3, qa0.w, a0);
        a1 = fmaf(k0, qb0.x, a1); a1 = fmaf(k1, qb0.y, a1);
        a1 = fmaf(k2, qb0.z, a1); a1 = fmaf(k3, qb0.w, a1);
        a0 = fmaf(k4, qa1.x, a0); a0 = fmaf(k5, qa1.y, a0);
        a0 = fmaf(k6, qa1.z, a0); a0 = fmaf(k7, qa1.w, a0);
        a1 = fmaf(k4, qb1.x, a1); a1 = fmaf(k5, qb1.y, a1);
        a1 = fmaf(k6, qb1.z, a1); a1 = fmaf(k7, qb1.w, a1);
      }
      if (qm && n >= NQUERY + NPREFIX) {
        int r0 = q0 + rg, r1 = q0 + rg + 4;
        int pk = n - (NQUERY + NPREFIX);
        if (r0 < NQUERY && !qm[(b * NQUERY + r0) * NPATCHES + pk]) a0 = -1e30f;
        if (r1 < NQUERY && !qm[(b * NQUERY + r1) * NPATCHES + pk]) a1 = -1e30f;
      }
      srow[n][(rg + ksw) & 7] = a0;
      srow[n][(rg + 4 + ksw) & 7] = a1;
    }
    if (more) {
#pragma unroll
      for (int i = 0; i < 8; i++) cur[i] = nxt[i];
    }
  }
  __syncthreads();

  // wave-parallel softmax: 32 lanes per row, 8 rows concurrently
  {
    const int r = tid >> 5, g = tid & 31;
    const int cs = (r + (g >> 2)) & 7;  // swizzled column, constant per thread
    float mx = -1e30f;
    for (int n = g; n < Ntok; n += 32) mx = fmaxf(mx, srow[n][cs]);
#pragma unroll
    for (int off = 16; off; off >>= 1) mx = fmaxf(mx, __shfl_xor(mx, off));
    float sum = 0.f;
    for (int n = g; n < Ntok; n += 32) {
      float e = __expf(srow[n][cs] - mx);
      srow[n][cs] = e;
      sum += e;
    }
#pragma unroll
    for (int off = 16; off; off >>= 1) sum += __shfl_xor(sum, off);
    if (g == 0) inv[r] = 1.0f / sum;
  }
  __syncthreads();

  const int d = tid & 63, qr = tid >> 6;
  float oacc[QT];
#pragma unroll
  for (int r = 0; r < QT; r++) oacc[r] = 0.f;
  const u16* vp = qkv + (size_t)b * Ntok * (3 * CH) + 2 * CH + h * DHEAD + d +
                  (size_t)qr * (3 * CH);
  int n = qr;
  for (; n + 28 < Ntok; n += 32) {
    float v0 = b2f(vp[0]);
    float v1 = b2f(vp[4 * 3 * CH]);
    float v2 = b2f(vp[8 * 3 * CH]);
    float v3 = b2f(vp[12 * 3 * CH]);
    float v4 = b2f(vp[16 * 3 * CH]);
    float v5 = b2f(vp[20 * 3 * CH]);
    float v6 = b2f(vp[24 * 3 * CH]);
    float v7 = b2f(vp[28 * 3 * CH]);
    AVROT(v0, n, 0);
    AVROT(v1, n + 4, 1);
    AVROT(v2, n + 8, 2);
    AVROT(v3, n + 12, 3);
    AVROT(v4, n + 16, 4);
    AVROT(v5, n + 20, 5);
    AVROT(v6, n + 24, 6);
    AVROT(v7, n + 28, 7);
    vp += 32 * 3 * CH;
  }
  // tail: rotation index continues from 0 at the 32-token block boundary
  for (int t = 0; n < Ntok; n += 4, t++) {
    float vv = b2f(vp[0]);
    switch (t) {
      case 0: AVROT(vv, n, 0); break;
      case 1: AVROT(vv, n, 1); break;
      case 2: AVROT(vv, n, 2); break;
      case 3: AVROT(vv, n, 3); break;
      case 4: AVROT(vv, n, 4); break;
      case 5: AVROT(vv, n, 5); break;
      case 6: AVROT(vv, n, 6); break;
      default: AVROT(vv, n, 7); break;
    }
    vp += 4 * 3 * CH;
  }
  __syncthreads();  // all srow reads done; reuse srow as [8][256] scratch
  float* tmp = &srow[0][0];
#pragma unroll
  for (int r = 0; r < QT; r++) tmp[r * 256 + tid] = oacc[r];
  __syncthreads();
#pragma unroll
  for (int p = 0; p < 2; p++) {
    int r = (p << 2) + qr;
    if (q0 + r < Ntok) {
      float t = (tmp[r * 256 + d] + tmp[r * 256 + 64 + d]) +
                (tmp[r * 256 + 128 + d] + tmp[r * 256 + 192 + d]);
      out[(size_t)(b * Ntok + q0 + r) * CH + h * DHEAD + d] = f2b(t * inv[r]);
    }
  }
}

// ---------------- misc elementwise ----------------
__global__ void k_patchify(const float* __restrict__ x, const float* __restrict__ mean,
                           const float* __restrict__ stdv, u16* __restrict__ xp) {
  int idx = blockIdx.x * 256 + threadIdx.x;
  if (idx >= BSZ * NPATCHES * CH) return;
  int f = idx % CH;
  int p = (idx / CH) % NPATCHES;
  int b = idx / (CH * NPATCHES);
  int c = f >> 8;
  int py = (f >> 4) & 15;
  int px = f & 15;
  int gy = p >> 5, gx = p & 31;
  float v = x[((size_t)(b * 3 + c) * IMGSZ + gy * 16 + py) * IMGSZ + gx * 16 + px];
  xp[idx] = f2b((v * (1.0f / 255.0f) - mean[c]) / stdv[c]);
}

__global__ void k_assemble(const float* __restrict__ xpe, const float* __restrict__ prefix,
                           const float* __restrict__ pos, float* __restrict__ X) {
  int idx = blockIdx.x * 256 + threadIdx.x;
  if (idx >= BSZ * NTOK1 * CH) return;
  int c = idx % CH;
  int n = (idx / CH) % NTOK1;
  int b = idx / (CH * NTOK1);
  float v;
  if (n < NPREFIX) v = prefix[n * CH + c];
  else v = xpe[((size_t)b * NPATCHES + n - NPREFIX) * CH + c] + pos[(size_t)(n - NPREFIX) * CH + c];
  X[idx] = v;
}

__global__ void k_concat(const float* __restrict__ Xin, const float* __restrict__ qe,
                         float* __restrict__ Xout) {
  int idx = blockIdx.x * 256 + threadIdx.x;
  if (idx >= BSZ * NTOK2 * CH) return;
  int c = idx % CH;
  int n = (idx / CH) % NTOK2;
  int b = idx / (CH * NTOK2);
  float v;
  if (n < NQUERY) v = qe[n * CH + c];
  else v = Xin[((size_t)b * NTOK1 + n - NQUERY) * CH + c];
  Xout[idx] = v;
}

// repack upt_w (s, c, o, d, x) -> WPb[s][dx*768+o][c], bf16
__global__ __launch_bounds__(256) void k_repack(const float* __restrict__ upt,
                                                u16* __restrict__ WPb) {
  __shared__ float t[4][32][33];
  int o0 = blockIdx.x * 32, c0 = blockIdx.y * 32, s = blockIdx.z;
  int tid = threadIdx.x;
  for (int idx = tid; idx < 32 * 128; idx += 256) {
    int cc = idx >> 7;
    int rest = idx & 127;
    int oo = rest >> 2, dx = rest & 3;
    t[dx][oo][cc] = upt[((size_t)(s * CH + c0 + cc) * CH + o0 + oo) * 4 + dx];
  }
  __syncthreads();
  for (int idx = tid; idx < 4 * 32 * 32; idx += 256) {
    int dx = idx >> 10;
    int oo = (idx >> 5) & 31;
    int cc = idx & 31;
    WPb[((size_t)(s * 4 + dx) * CH + o0 + oo) * CH + c0 + cc] = f2b(t[dx][oo][cc]);
  }
}

// antialiased bilinear 128->32 downsample + threshold>0
__global__ void k_qmask(const float* __restrict__ mlog, unsigned char* __restrict__ qm) {
  int idx = blockIdx.x * 256 + threadIdx.x;
  if (idx >= BSZ * NQUERY * NPATCHES) return;
  int gx = idx & 31;
  int gy = (idx >> 5) & 31;
  int bq = idx >> 10;
  const float* m = mlog + (size_t)bq * 16384;
  float cy = 4.0f * gy + 1.5f, cx = 4.0f * gx + 1.5f;
  int y0 = max(0, 4 * gy - 2), y1 = min(127, 4 * gy + 5);
  int x0 = max(0, 4 * gx - 2), x1 = min(127, 4 * gx + 5);
  float num = 0.f;
  for (int jy = y0; jy <= y1; jy++) {
    float wy = 1.0f - fabsf((float)jy - cy) * 0.25f;
    float rowsum = 0.f;
    for (int jx = x0; jx <= x1; jx++) {
      float wx = 1.0f - fabsf((float)jx - cx) * 0.25f;
      rowsum = fmaf(wx, m[jy * 128 + jx], rowsum);
    }
    num = fmaf(wy, rowsum, num);
  }
  qm[idx] = (num > 0.0f) ? 1 : 0;
}

// ---------------- host orchestration ----------------
extern "C" void kernel_launch(void* const* d_in, const int* in_sizes, int n_in,
                              void* d_out_v, int out_size, void* d_ws, size_t ws_size,
                              hipStream_t stream) {
  (void)in_sizes; (void)n_in; (void)out_size; (void)ws_size;
  const float* x_in    = (const float*)d_in[0];
  const float* pmean   = (const float*)d_in[1];
  const float* pstd    = (const float*)d_in[2];
  const float* patch_w = (const float*)d_in[3];
  const float* patch_b = (const float*)d_in[4];
  const float* pos     = (const float*)d_in[5];
  const float* prefix  = (const float*)d_in[6];
  const float* qkv_w   = (const float*)d_in[7];
  const float* qkv_b   = (const float*)d_in[8];
  const float* proj_w  = (const float*)d_in[9];
  const float* proj_b  = (const float*)d_in[10];
  const float* ln1w    = (const float*)d_in[11];
  const float* ln1b    = (const float*)d_in[12];
  const float* ln2w    = (const float*)d_in[13];
  const float* ln2b    = (const float*)d_in[14];
  const float* ls1     = (const float*)d_in[15];
  const float* ls2     = (const float*)d_in[16];
  const float* fc1w    = (const float*)d_in[17];
  const float* fc1b    = (const float*)d_in[18];
  const float* fc2w    = (const float*)d_in[19];
  const float* fc2b    = (const float*)d_in[20];
  const float* normw   = (const float*)d_in[21];
  const float* normb   = (const float*)d_in[22];
  const float* qemb    = (const float*)d_in[23];
  const float* clsw    = (const float*)d_in[24];
  const float* clsb    = (const float*)d_in[25];
  const float* mh1w    = (const float*)d_in[26];
  const float* mh1b    = (const float*)d_in[27];
  const float* mh2w    = (const float*)d_in[28];
  const float* mh2b    = (const float*)d_in[29];
  const float* mh3w    = (const float*)d_in[30];
  const float* mh3b    = (const float*)d_in[31];
  const float* uptw    = (const float*)d_in[32];
  const float* uptb    = (const float*)d_in[33];
  const float* updww   = (const float*)d_in[34];
  const float* uplnw   = (const float*)d_in[35];
  const float* uplnb   = (const float*)d_in[36];

  float* out = (float*)d_out_v;
  float* out_mask = out;                                   // (5,2,100,128,128)
  float* out_cls = out + (size_t)5 * BSZ * NQUERY * 16384; // (5,2,100,151)

  char* base = (char*)d_ws;
  size_t off = 0;
  auto allocB = [&](size_t bytes) {
    void* p = base + off;
    off += (bytes + 63) & ~(size_t)63;
    return p;
  };
  // fp32
  float* Xa = (float*)allocB((size_t)BSZ * NTOK2 * CH * 4);
  float* Xb = (float*)allocB((size_t)BSZ * NTOK2 * CH * 4);
  float* Hf = (float*)allocB((size_t)BSZ * NTOK2 * CH * 4);   // XPE staging
  // bf16
  u16* Wq  = (u16*)allocB((size_t)3 * CH * CH * 2);
  u16* Wp  = (u16*)allocB((size_t)CH * CH * 2);
  u16* Wf1 = (u16*)allocB((size_t)4 * CH * CH * 2);
  u16* Wf2 = (u16*)allocB((size_t)CH * 4 * CH * 2);
  u16* Wpa = (u16*)allocB((size_t)CH * CH * 2);
  u16* Wcl = (u16*)allocB((size_t)NCLASS * CH * 2);
  u16* Wm1 = (u16*)allocB((size_t)CH * CH * 2);
  u16* Wm2 = (u16*)allocB((size_t)CH * CH * 2);
  u16* Wm3 = (u16*)allocB((size_t)CH * CH * 2);
  u16* WPb = (u16*)allocB((size_t)2 * 4 * CH * CH * 2);
  u16* LNb = (u16*)allocB((size_t)BSZ * NTOK2 * CH * 2);
  u16* AOb = (u16*)allocB((size_t)BSZ * NTOK2 * CH * 2);
  u16* XPb = (u16*)allocB((size_t)BSZ * NPATCHES * CH * 2);
  u16* HQa = (u16*)allocB((size_t)BSZ * NQUERY * CH * 2);
  u16* HQb = (u16*)allocB((size_t)BSZ * NQUERY * CH * 2);
  u16* HQc = (u16*)allocB((size_t)BSZ * NQUERY * CH * 2);
  u16* LNq = (u16*)allocB((size_t)BSZ * NQUERY * CH * 2);
  u16* LNp = (u16*)allocB((size_t)BSZ * NPATCHES * CH * 2);
  // big shared region: predict pipeline (dual batch) + layer-loop aliases
  u16* Sb  = (u16*)allocB(((size_t)4 * 4096 * CH + (size_t)4 * 16384 * CH) * 2);
  unsigned char* QM = (unsigned char*)allocB((size_t)BSZ * NQUERY * NPATCHES);

  u16* s0g  = Sb;                                   // [2][4096][768]
  u16* s0l  = Sb + (size_t)2 * 4096 * CH;           // [2][4096][768]
  u16* s1g  = Sb + (size_t)4 * 4096 * CH;           // [2][16384][768]
  u16* s1d  = s1g + (size_t)2 * 16384 * CH;         // [2][16384][768]
  u16* QKVb = Sb;                                   // rows x 2304 (layer loop)
  u16* M1b  = Sb;                                   // rows x 3072 (layer loop)

  auto bgemm = [&](const u16* A, const u16* B, const float* bias, float* Cf, u16* Cb,
                   int M, int N, int K, int lda, int ldb, int ldcf, int ldcb,
                   int flags, int lp2w, const float* lsv) {
    dim3 g((N + 127) / 128, (M + 127) / 128);
    k_bgemm<<<g, 256, 0, stream>>>(A, B, bias, Cf, Cb, M, N, K, lda, ldb, ldcf, ldcb,
                                   flags, lp2w, lsv, 0, 0, 0);
  };
  auto cvt = [&](const float* s, u16* d, int n) {
    k_cvt<<<(n / 4 + 255) / 256, 256, 0, stream>>>(s, d, n);
  };
  auto ew = [&](long tot) { return dim3((unsigned)((tot + 255) / 256)); };

  // ---- one-time weight conversions ----
  cvt(patch_w, Wpa, CH * CH);
  cvt(clsw, Wcl, NCLASS * CH);
  cvt(mh1w, Wm1, CH * CH);
  cvt(mh2w, Wm2, CH * CH);
  cvt(mh3w, Wm3, CH * CH);
  k_repack<<<dim3(24, 24, 2), 256, 0, stream>>>(uptw, WPb);

  // ---- patch embedding ----
  k_patchify<<<ew((long)BSZ * NPATCHES * CH), 256, 0, stream>>>(x_in, pmean, pstd, XPb);
  bgemm(XPb, Wpa, patch_b, Hf, nullptr, BSZ * NPATCHES, CH, CH, CH, CH, CH, 0, 0, 0, nullptr);
  k_assemble<<<ew((long)BSZ * NTOK1 * CH), 256, 0, stream>>>(Hf, prefix, pos, Xa);

  float* X = Xa;
  float* Xalt = Xb;

  auto predict = [&](float* Xcur, int pred, bool build_mask) {
    k_lnp<<<dim3(BSZ * NTOK2), 256, 0, stream>>>(Xcur, normw, normb, LNq, LNp);
    bgemm(LNq, Wcl, clsb, out_cls + (size_t)pred * BSZ * NQUERY * NCLASS, nullptr,
          BSZ * NQUERY, NCLASS, CH, CH, CH, NCLASS, 0, 0, 0, nullptr);
    bgemm(LNq, Wm1, mh1b, nullptr, HQa, BSZ * NQUERY, CH, CH, CH, CH, 0, CH, 1, 0, nullptr);
    bgemm(HQa, Wm2, mh2b, nullptr, HQb, BSZ * NQUERY, CH, CH, CH, CH, 0, CH, 1, 0, nullptr);
    bgemm(HQb, Wm3, mh3b, nullptr, HQc, BSZ * NQUERY, CH, CH, CH, CH, 0, CH, 0, 0, nullptr);
    // dual-batch upsample pipeline
    bgemm(LNp, WPb, uptb, nullptr, s0g,
          BSZ * 1024, 4 * CH, CH, CH, CH, 0, 0, 2, 5, nullptr);
    k_dwln<<<dim3(BSZ * 4096), 256, 0, stream>>>(s0g, updww, uplnw, uplnb, s0l, 64, 64);
    bgemm(s0l, WPb + (size_t)4 * CH * CH, uptb + CH, nullptr, s1g,
          BSZ * 4096, 4 * CH, CH, CH, CH, 0, 0, 2, 6, nullptr);
    k_dwln<<<dim3(BSZ * 16384), 256, 0, stream>>>(s1g, updww + CH * 9, uplnw + CH,
                                                  uplnb + CH, s1d, 128, 128);
    // mask logits: z-batched over both images (z strides select A/B/C slices)
    {
      dim3 g(16384 / 128, 1, BSZ);
      k_bgemm<<<g, 256, 0, stream>>>(
          HQc, s1d, nullptr,
          out_mask + (size_t)pred * BSZ * NQUERY * 16384, nullptr,
          NQUERY, 16384, CH, CH, CH, 16384, 0, 0, 0, nullptr,
          (long long)NQUERY * CH, (long long)16384 * CH, (long long)NQUERY * 16384);
    }
    if (build_mask) {
      k_qmask<<<ew((long)BSZ * NQUERY * NPATCHES), 256, 0, stream>>>(
          out_mask + (size_t)pred * BSZ * NQUERY * 16384, QM);
    }
  };

  int Ntok = NTOK1;
  for (int i = 0; i < LAYERS; i++) {
    if (i == LAYERS - NBLK) {
      k_concat<<<ew((long)BSZ * NTOK2 * CH), 256, 0, stream>>>(X, qemb, Xalt);
      float* t = X; X = Xalt; Xalt = t;
      Ntok = NTOK2;
    }
    if (i >= LAYERS - NBLK) predict(X, i - (LAYERS - NBLK), true);
    const int rows = BSZ * Ntok;
    // per-layer weight conversion (single dispatch)
    k_cvt_layer<<<dim3(3456), 256, 0, stream>>>(
        qkv_w + (size_t)i * 3 * CH * CH, proj_w + (size_t)i * CH * CH,
        fc1w + (size_t)i * 4 * CH * CH, fc2w + (size_t)i * CH * 4 * CH,
        Wq, Wp, Wf1, Wf2);
    // attention block
    k_ln<float><<<dim3(rows), 256, 0, stream>>>(X, ln1w + i * CH, ln1b + i * CH, LNb);
    bgemm(LNb, Wq, qkv_b + (size_t)i * 3 * CH, nullptr, QKVb,
          rows, 3 * CH, CH, CH, CH, 0, 3 * CH, 0, 0, nullptr);
    k_attn<<<dim3((Ntok + QT - 1) / QT, 12, BSZ), 256, 0, stream>>>(
        QKVb, AOb, (i >= LAYERS - NBLK) ? QM : (const unsigned char*)nullptr, Ntok);
    bgemm(AOb, Wp, proj_b + (size_t)i * CH, X, nullptr,
          rows, CH, CH, CH, CH, CH, 0, 4, 0, ls1 + i * CH);  // fused residual
    // MLP block
    k_ln<float><<<dim3(rows), 256, 0, stream>>>(X, ln2w + i * CH, ln2b + i * CH, LNb);
    bgemm(LNb, Wf1, fc1b + (size_t)i * 4 * CH, nullptr, M1b,
          rows, 4 * CH, CH, CH, CH, 0, 4 * CH, 1, 0, nullptr);
    bgemm(M1b, Wf2, fc2b + (size_t)i * CH, X, nullptr,
          rows, CH, 4 * CH, 4 * CH, 4 * CH, CH, 0, 4, 0, ls2 + i * CH);  // fused residual
  }
  predict(X, 4, false);
}

// Round 14
// 9657.330 us; speedup vs baseline: 1.3251x; 1.3251x over previous
//
#include <hip/hip_runtime.h>
#include <cmath>

// ---------------- constants ----------------
namespace {
constexpr int BSZ = 2;
constexpr int IMGSZ = 512;
constexpr int NPATCHES = 1024;
constexpr int CH = 768;
constexpr int LAYERS = 12;
constexpr int DHEAD = 64;
constexpr int NQUERY = 100;
constexpr int NPREFIX = 5;
constexpr int NCLASS = 151;
constexpr int NBLK = 4;
constexpr int NTOK1 = NPREFIX + NPATCHES;          // 1029
constexpr int NTOK2 = NQUERY + NPREFIX + NPATCHES; // 1129
constexpr int QT = 8;
}

typedef unsigned short u16;
typedef __bf16 bf16x8 __attribute__((ext_vector_type(8)));
typedef float floatx4 __attribute__((ext_vector_type(4)));

__device__ __forceinline__ float geluf(float v) {
  return 0.5f * v * (1.0f + erff(v * 0.70710678118654752f));
}
__device__ __forceinline__ u16 f2b(float f) {
  unsigned u = __float_as_uint(f);
  u += 0x7fffu + ((u >> 16) & 1u);
  return (u16)(u >> 16);
}
__device__ __forceinline__ float b2f(u16 v) {
  return __uint_as_float(((unsigned)v) << 16);
}
__device__ __forceinline__ float b2f_lo(unsigned u) {
  return __uint_as_float(u << 16);
}
__device__ __forceinline__ float b2f_hi(unsigned u) {
  return __uint_as_float(u & 0xffff0000u);
}
__device__ __forceinline__ void gl_lds16(const u16* g, u16* l) {
  __builtin_amdgcn_global_load_lds((const __attribute__((address_space(1))) void*)g,
                                   (__attribute__((address_space(3))) void*)l, 16, 0, 0);
}
__device__ __forceinline__ float ldv(const float* p) { return *p; }
__device__ __forceinline__ float ldv(const u16* p) { return b2f(*p); }

// ---------------- fp32 -> bf16 convert (n % 4 == 0) ----------------
__global__ void k_cvt(const float* __restrict__ s, u16* __restrict__ d, int n) {
  int i = (blockIdx.x * 256 + threadIdx.x) * 4;
  if (i >= n) return;
  float4 v = *(const float4*)(s + i);
  u16 r[4] = {f2b(v.x), f2b(v.y), f2b(v.z), f2b(v.w)};
  *(uint2*)(d + i) = *(const uint2*)r;
}

// one dispatch converts all four per-layer weight tensors
__global__ __launch_bounds__(256) void k_cvt_layer(
    const float* __restrict__ qw, const float* __restrict__ pw,
    const float* __restrict__ f1, const float* __restrict__ f2,
    u16* __restrict__ dq, u16* __restrict__ dp,
    u16* __restrict__ df1, u16* __restrict__ df2) {
  constexpr size_t CC = (size_t)CH * CH;
  size_t i = ((size_t)blockIdx.x * 256 + threadIdx.x) * 8;
  if (i >= 12 * CC) return;
  const float* s; u16* d; size_t o;
  if (i < 3 * CC)      { s = qw; d = dq;  o = i; }
  else if (i < 4 * CC) { s = pw; d = dp;  o = i - 3 * CC; }
  else if (i < 8 * CC) { s = f1; d = df1; o = i - 4 * CC; }
  else                 { s = f2; d = df2; o = i - 8 * CC; }
  float4 a = *(const float4*)(s + o);
  float4 b = *(const float4*)(s + o + 4);
  u16 r[8] = {f2b(a.x), f2b(a.y), f2b(a.z), f2b(a.w),
              f2b(b.x), f2b(b.y), f2b(b.z), f2b(b.w)};
  *(uint4*)(d + o) = *(const uint4*)r;
}

// ---------------- bf16 MFMA GEMM (m97 structure) ----------------
// C[m,n] = sum_k A[m,k] * B[n,k];  A: M x K (lda), B: N x K (ldb), both bf16
// flags: 1 = gelu; 2 = upsample scatter (multi-batch); 4 = fused residual.
// zA/zB/zC: per-blockIdx.z element offsets (0 when gridDim.z == 1).
__global__ __launch_bounds__(256) void k_bgemm(
    const u16* __restrict__ A, const u16* __restrict__ B,
    const float* __restrict__ bias,
    float* __restrict__ Cf, u16* __restrict__ Cb,
    int M, int N, int K, int lda, int ldb, int ldcf, int ldcb,
    int flags, int lp2w, const float* __restrict__ lsv,
    long long zA, long long zB, long long zC) {
  __shared__ u16 As[128 * 32];
  __shared__ u16 Bs[128 * 32];
  const int tid = threadIdx.x;
  const int zz = blockIdx.z;
  A += (size_t)zz * zA;
  B += (size_t)zz * zB;
  if (Cf) Cf += (size_t)zz * zC;
  if (Cb) Cb += (size_t)zz * zC;
  const int m0 = blockIdx.y << 7, n0 = blockIdx.x << 7;
  const int wv = tid >> 6, ln = tid & 63;
  const int wm = (wv >> 1) << 6, wn = (wv & 1) << 6;
  const int fr = ln & 15, fq = ln >> 4;
  floatx4 acc[4][4];
#pragma unroll
  for (int i = 0; i < 4; i++)
#pragma unroll
    for (int j = 0; j < 4; j++) acc[i][j] = (floatx4){0.f, 0.f, 0.f, 0.f};

  const int c0 = tid, c1 = tid + 256;
  const u16* Ag0 = A + (size_t)min(m0 + (c0 >> 2), M - 1) * lda + ((c0 & 3) << 3);
  const u16* Ag1 = A + (size_t)min(m0 + (c1 >> 2), M - 1) * lda + ((c1 & 3) << 3);
  const u16* Bg0 = B + (size_t)min(n0 + (c0 >> 2), N - 1) * ldb + ((c0 & 3) << 3);
  const u16* Bg1 = B + (size_t)min(n0 + (c1 >> 2), N - 1) * ldb + ((c1 & 3) << 3);
  u16* Al0 = As + c0 * 8;
  u16* Al1 = As + c1 * 8;
  u16* Bl0 = Bs + c0 * 8;
  u16* Bl1 = Bs + c1 * 8;

  for (int k0 = 0; k0 < K; k0 += 32) {
    gl_lds16(Ag0, Al0);
    gl_lds16(Ag1, Al1);
    gl_lds16(Bg0, Bl0);
    gl_lds16(Bg1, Bl1);
    Ag0 += 32; Ag1 += 32; Bg0 += 32; Bg1 += 32;
    __syncthreads();
    bf16x8 af[4], bb[4];
#pragma unroll
    for (int mi = 0; mi < 4; mi++)
      af[mi] = *(const bf16x8*)(As + ((wm + (mi << 4) + fr) << 5) + (fq << 3));
#pragma unroll
    for (int ni = 0; ni < 4; ni++)
      bb[ni] = *(const bf16x8*)(Bs + ((wn + (ni << 4) + fr) << 5) + (fq << 3));
#pragma unroll
    for (int mi = 0; mi < 4; mi++)
#pragma unroll
      for (int ni = 0; ni < 4; ni++)
        acc[mi][ni] = __builtin_amdgcn_mfma_f32_16x16x32_bf16(af[mi], bb[ni], acc[mi][ni], 0, 0, 0);
    __syncthreads();
  }

  // C/D layout: col = lane&15 (n), row = (lane>>4)*4 + reg (m)  [m89-verified]
#pragma unroll
  for (int mi = 0; mi < 4; mi++) {
#pragma unroll
    for (int ni = 0; ni < 4; ni++) {
#pragma unroll
      for (int r = 0; r < 4; r++) {
        int m = m0 + wm + (mi << 4) + (fq << 2) + r;
        int n = n0 + wn + (ni << 4) + fr;
        if (m >= M || n >= N) continue;
        float v = acc[mi][ni][r];
        if (flags & 2) {
          int o = n % 768, dx = n / 768;
          v = geluf(v + bias[o]);
          int W = 1 << lp2w;
          int bidx = m >> (2 * lp2w);
          int mloc = m & ((1 << (2 * lp2w)) - 1);
          int y = mloc >> lp2w, x = mloc & (W - 1);
          size_t dp = ((size_t)y << (lp2w + 2)) + ((size_t)x << 1) +
                      ((size_t)(dx >> 1) << (lp2w + 1)) + (dx & 1) +
                      ((size_t)bidx << (2 * lp2w + 2));
          Cb[dp * 768 + o] = f2b(v);
        } else {
          if (bias) v += bias[n];
          if (flags & 1) v = geluf(v);
          if (flags & 4) {
            float* p = Cf + (size_t)m * ldcf + n;
            *p += lsv[n] * v;
          } else {
            if (Cf) Cf[(size_t)m * ldcf + n] = v;
            if (Cb) Cb[(size_t)m * ldcb + n] = f2b(v);
          }
        }
      }
    }
  }
}

// ---------------- row LayerNorm over 768, bf16 out (1-barrier) ----------------
template <typename T>
__global__ __launch_bounds__(256) void k_ln(const T* __restrict__ X,
                                            const float* __restrict__ w,
                                            const float* __restrict__ b,
                                            u16* __restrict__ out) {
  const int row = blockIdx.x, tid = threadIdx.x;
  const T* xr = X + (size_t)row * CH;
  float v0 = ldv(xr + tid), v1 = ldv(xr + tid + 256), v2 = ldv(xr + tid + 512);
  float s = v0 + v1 + v2;
  float q = v0 * v0 + v1 * v1 + v2 * v2;
#pragma unroll
  for (int off = 32; off; off >>= 1) {
    s += __shfl_xor(s, off);
    q += __shfl_xor(q, off);
  }
  __shared__ float sh[8];
  const int wv = tid >> 6;
  if ((tid & 63) == 0) { sh[wv] = s; sh[4 + wv] = q; }
  __syncthreads();
  s = (sh[0] + sh[1]) + (sh[2] + sh[3]);
  q = (sh[4] + sh[5]) + (sh[6] + sh[7]);
  float m = s * (1.0f / CH);
  float rstd = rsqrtf(fmaxf(q * (1.0f / CH) - m * m, 0.f) + 1e-6f);
  u16* orow = out + (size_t)row * CH;
  orow[tid]       = f2b((v0 - m) * rstd * w[tid]       + b[tid]);
  orow[tid + 256] = f2b((v1 - m) * rstd * w[tid + 256] + b[tid + 256]);
  orow[tid + 512] = f2b((v2 - m) * rstd * w[tid + 512] + b[tid + 512]);
}

// predict LN: routes query rows -> outq (contiguous 2x100), patch rows -> outp
// (contiguous per batch 2x1024); prefix rows skipped (unused downstream).
__global__ __launch_bounds__(256) void k_lnp(const float* __restrict__ X,
                                             const float* __restrict__ w,
                                             const float* __restrict__ b,
                                             u16* __restrict__ outq,
                                             u16* __restrict__ outp) {
  const int row = blockIdx.x, tid = threadIdx.x;
  const int bb = row / NTOK2, n = row - bb * NTOK2;
  u16* orow;
  if (n < NQUERY) orow = outq + (size_t)(bb * NQUERY + n) * CH;
  else if (n >= NQUERY + NPREFIX)
    orow = outp + (size_t)(bb * NPATCHES + (n - NQUERY - NPREFIX)) * CH;
  else return;
  const float* xr = X + (size_t)row * CH;
  float v0 = ldv(xr + tid), v1 = ldv(xr + tid + 256), v2 = ldv(xr + tid + 512);
  float s = v0 + v1 + v2;
  float q = v0 * v0 + v1 * v1 + v2 * v2;
#pragma unroll
  for (int off = 32; off; off >>= 1) {
    s += __shfl_xor(s, off);
    q += __shfl_xor(q, off);
  }
  __shared__ float sh[8];
  const int wv = tid >> 6;
  if ((tid & 63) == 0) { sh[wv] = s; sh[4 + wv] = q; }
  __syncthreads();
  s = (sh[0] + sh[1]) + (sh[2] + sh[3]);
  q = (sh[4] + sh[5]) + (sh[6] + sh[7]);
  float m = s * (1.0f / CH);
  float rstd = rsqrtf(fmaxf(q * (1.0f / CH) - m * m, 0.f) + 1e-6f);
  orow[tid]       = f2b((v0 - m) * rstd * w[tid]       + b[tid]);
  orow[tid + 256] = f2b((v1 - m) * rstd * w[tid + 256] + b[tid + 256]);
  orow[tid + 512] = f2b((v2 - m) * rstd * w[tid + 512] + b[tid + 512]);
}

// ---------------- fused depthwise 3x3 conv + LayerNorm (multi-batch) ---------
__global__ __launch_bounds__(256) void k_dwln(const u16* __restrict__ in,
                                              const float* __restrict__ w9,
                                              const float* __restrict__ lw,
                                              const float* __restrict__ lb,
                                              u16* __restrict__ out, int H, int W) {
  const int HW = H * W;
  int pix = blockIdx.x;
  const int bo = pix / HW;
  pix -= bo * HW;
  in += (size_t)bo * HW * CH;
  out += (size_t)bo * HW * CH;
  const int tid = threadIdx.x;
  const int x = pix % W, y = pix / W;
  float acc[3];
#pragma unroll
  for (int j = 0; j < 3; j++) {
    const int c = tid + (j << 8);
    const float* wp = w9 + c * 9;
    float sacc = 0.f;
#pragma unroll
    for (int ky = 0; ky < 3; ky++) {
      int yy = y + ky - 1;
      if (yy < 0 || yy >= H) continue;
#pragma unroll
      for (int kx = 0; kx < 3; kx++) {
        int xx = x + kx - 1;
        if (xx < 0 || xx >= W) continue;
        sacc = fmaf(wp[ky * 3 + kx], b2f(in[((size_t)yy * W + xx) * CH + c]), sacc);
      }
    }
    acc[j] = sacc;
  }
  float s = acc[0] + acc[1] + acc[2];
  float q = acc[0] * acc[0] + acc[1] * acc[1] + acc[2] * acc[2];
#pragma unroll
  for (int off = 32; off; off >>= 1) {
    s += __shfl_xor(s, off);
    q += __shfl_xor(q, off);
  }
  __shared__ float sh[8];
  const int wv = tid >> 6;
  if ((tid & 63) == 0) { sh[wv] = s; sh[4 + wv] = q; }
  __syncthreads();
  s = (sh[0] + sh[1]) + (sh[2] + sh[3]);
  q = (sh[4] + sh[5]) + (sh[6] + sh[7]);
  float m = s * (1.0f / CH);
  float rstd = rsqrtf(fmaxf(q * (1.0f / CH) - m * m, 0.f) + 1e-6f);
  u16* orow = out + (size_t)pix * CH;
#pragma unroll
  for (int j = 0; j < 3; j++) {
    const int c = tid + (j << 8);
    orow[c] = f2b((acc[j] - m) * rstd * lw[c] + lb[c]);
  }
}

// ---------------- fused attention (bf16 in/out, fp32 math) ----------------
// R12 version (best measured, bit-exact): QT=8, 4 blocks/CU, K double-buffered
// in plain locals, srow [token][8] with column-rotation swizzle (0 conflicts).
// NOTE (R13 lesson): do NOT hoist qs into registers — any >~16 extra
// long-lived VGPRs spills to scratch under the 4-wave budget (WRITE_SIZE
// 9 MB -> 146 MB, dur 355 -> 620 us). qs reads are wave-uniform broadcasts.
#define AVROT(VV, NN, J)                                       \
  do {                                                         \
    float4 pa = *(const float4*)&srow[(NN)][0];                \
    float4 pb = *(const float4*)&srow[(NN)][4];                \
    oacc[(0 - (J)) & 7] = fmaf(pa.x, (VV), oacc[(0 - (J)) & 7]); \
    oacc[(1 - (J)) & 7] = fmaf(pa.y, (VV), oacc[(1 - (J)) & 7]); \
    oacc[(2 - (J)) & 7] = fmaf(pa.z, (VV), oacc[(2 - (J)) & 7]); \
    oacc[(3 - (J)) & 7] = fmaf(pa.w, (VV), oacc[(3 - (J)) & 7]); \
    oacc[(4 - (J)) & 7] = fmaf(pb.x, (VV), oacc[(4 - (J)) & 7]); \
    oacc[(5 - (J)) & 7] = fmaf(pb.y, (VV), oacc[(5 - (J)) & 7]); \
    oacc[(6 - (J)) & 7] = fmaf(pb.z, (VV), oacc[(6 - (J)) & 7]); \
    oacc[(7 - (J)) & 7] = fmaf(pb.w, (VV), oacc[(7 - (J)) & 7]); \
  } while (0)

__global__ __launch_bounds__(256, 4) void k_attn(const u16* __restrict__ qkv,
                                                 u16* __restrict__ out,
                                                 const unsigned char* __restrict__ qm,
                                                 int Ntok) {
  const int b = blockIdx.z, h = blockIdx.y, q0 = blockIdx.x * QT;
  const int tid = threadIdx.x;
  __shared__ float qs[QT][DHEAD];
  __shared__ float srow[1152][QT];   // [token][col] with rotation swizzle
  __shared__ float inv[QT];

  for (int idx = tid; idx < QT * DHEAD; idx += 256) {
    int r = idx >> 6, d = idx & 63;
    float v = 0.f;
    if (q0 + r < Ntok) v = b2f(qkv[(size_t)(b * Ntok + q0 + r) * (3 * CH) + h * DHEAD + d]) * 0.125f;
    qs[r][d] = v;
  }
  __syncthreads();

  const int jj = tid & 63, rg = tid >> 6;
  const u16* kbase = qkv + (size_t)b * Ntok * (3 * CH) + CH + h * DHEAD;

  uint4 cur[8], nxt[8];
  {
    const u16* kp = kbase + (size_t)min(jj, Ntok - 1) * (3 * CH);
#pragma unroll
    for (int i = 0; i < 8; i++) cur[i] = *(const uint4*)(kp + i * 8);
  }
  const int ksw = (jj >> 2) & 7;  // == ((nb+jj)>>2)&7 since nb % 64 == 0
  for (int nb = 0; nb < Ntok; nb += 64) {
    const bool more = (nb + 64 < Ntok);
    if (more) {
      const u16* np = kbase + (size_t)min(nb + 64 + jj, Ntok - 1) * (3 * CH);
#pragma unroll
      for (int i = 0; i < 8; i++) nxt[i] = *(const uint4*)(np + i * 8);
    }
    const int n = nb + jj;
    if (n < Ntok) {
      float a0 = 0.f, a1 = 0.f;
#pragma unroll
      for (int i = 0; i < 8; i++) {
        const int d = i << 3;
        float k0 = b2f_lo(cur[i].x), k1 = b2f_hi(cur[i].x);
        float k2 = b2f_lo(cur[i].y), k3 = b2f_hi(cur[i].y);
        float k4 = b2f_lo(cur[i].z), k5 = b2f_hi(cur[i].z);
        float k6 = b2f_lo(cur[i].w), k7 = b2f_hi(cur[i].w);
        float4 qa0 = *(const float4*)&qs[rg][d];
        float4 qb0 = *(const float4*)&qs[rg + 4][d];
        float4 qa1 = *(const float4*)&qs[rg][d + 4];
        float4 qb1 = *(const float4*)&qs[rg + 4][d + 4];
        a0 = fmaf(k0, qa0.x, a0); a0 = fmaf(k1, qa0.y, a0);
        a0 = fmaf(k2, qa0.z, a0); a0 = fmaf(k3, qa0.w, a0);
        a1 = fmaf(k0, qb0.x, a1); a1 = fmaf(k1, qb0.y, a1);
        a1 = fmaf(k2, qb0.z, a1); a1 = fmaf(k3, qb0.w, a1);
        a0 = fmaf(k4, qa1.x, a0); a0 = fmaf(k5, qa1.y, a0);
        a0 = fmaf(k6, qa1.z, a0); a0 = fmaf(k7, qa1.w, a0);
        a1 = fmaf(k4, qb1.x, a1); a1 = fmaf(k5, qb1.y, a1);
        a1 = fmaf(k6, qb1.z, a1); a1 = fmaf(k7, qb1.w, a1);
      }
      if (qm && n >= NQUERY + NPREFIX) {
        int r0 = q0 + rg, r1 = q0 + rg + 4;
        int pk = n - (NQUERY + NPREFIX);
        if (r0 < NQUERY && !qm[(b * NQUERY + r0) * NPATCHES + pk]) a0 = -1e30f;
        if (r1 < NQUERY && !qm[(b * NQUERY + r1) * NPATCHES + pk]) a1 = -1e30f;
      }
      srow[n][(rg + ksw) & 7] = a0;
      srow[n][(rg + 4 + ksw) & 7] = a1;
    }
    if (more) {
#pragma unroll
      for (int i = 0; i < 8; i++) cur[i] = nxt[i];
    }
  }
  __syncthreads();

  // wave-parallel softmax: 32 lanes per row, 8 rows concurrently
  {
    const int r = tid >> 5, g = tid & 31;
    const int cs = (r + (g >> 2)) & 7;  // swizzled column, constant per thread
    float mx = -1e30f;
    for (int n = g; n < Ntok; n += 32) mx = fmaxf(mx, srow[n][cs]);
#pragma unroll
    for (int off = 16; off; off >>= 1) mx = fmaxf(mx, __shfl_xor(mx, off));
    float sum = 0.f;
    for (int n = g; n < Ntok; n += 32) {
      float e = __expf(srow[n][cs] - mx);
      srow[n][cs] = e;
      sum += e;
    }
#pragma unroll
    for (int off = 16; off; off >>= 1) sum += __shfl_xor(sum, off);
    if (g == 0) inv[r] = 1.0f / sum;
  }
  __syncthreads();

  const int d = tid & 63, qr = tid >> 6;
  float oacc[QT];
#pragma unroll
  for (int r = 0; r < QT; r++) oacc[r] = 0.f;
  const u16* vp = qkv + (size_t)b * Ntok * (3 * CH) + 2 * CH + h * DHEAD + d +
                  (size_t)qr * (3 * CH);
  int n = qr;
  for (; n + 28 < Ntok; n += 32) {
    float v0 = b2f(vp[0]);
    float v1 = b2f(vp[4 * 3 * CH]);
    float v2 = b2f(vp[8 * 3 * CH]);
    float v3 = b2f(vp[12 * 3 * CH]);
    float v4 = b2f(vp[16 * 3 * CH]);
    float v5 = b2f(vp[20 * 3 * CH]);
    float v6 = b2f(vp[24 * 3 * CH]);
    float v7 = b2f(vp[28 * 3 * CH]);
    AVROT(v0, n, 0);
    AVROT(v1, n + 4, 1);
    AVROT(v2, n + 8, 2);
    AVROT(v3, n + 12, 3);
    AVROT(v4, n + 16, 4);
    AVROT(v5, n + 20, 5);
    AVROT(v6, n + 24, 6);
    AVROT(v7, n + 28, 7);
    vp += 32 * 3 * CH;
  }
  // tail: rotation index continues from 0 at the 32-token block boundary
  for (int t = 0; n < Ntok; n += 4, t++) {
    float vv = b2f(vp[0]);
    switch (t) {
      case 0: AVROT(vv, n, 0); break;
      case 1: AVROT(vv, n, 1); break;
      case 2: AVROT(vv, n, 2); break;
      case 3: AVROT(vv, n, 3); break;
      case 4: AVROT(vv, n, 4); break;
      case 5: AVROT(vv, n, 5); break;
      case 6: AVROT(vv, n, 6); break;
      default: AVROT(vv, n, 7); break;
    }
    vp += 4 * 3 * CH;
  }
  __syncthreads();  // all srow reads done; reuse srow as [8][256] scratch
  float* tmp = &srow[0][0];
#pragma unroll
  for (int r = 0; r < QT; r++) tmp[r * 256 + tid] = oacc[r];
  __syncthreads();
#pragma unroll
  for (int p = 0; p < 2; p++) {
    int r = (p << 2) + qr;
    if (q0 + r < Ntok) {
      float t = (tmp[r * 256 + d] + tmp[r * 256 + 64 + d]) +
                (tmp[r * 256 + 128 + d] + tmp[r * 256 + 192 + d]);
      out[(size_t)(b * Ntok + q0 + r) * CH + h * DHEAD + d] = f2b(t * inv[r]);
    }
  }
}

// ---------------- misc elementwise ----------------
__global__ void k_patchify(const float* __restrict__ x, const float* __restrict__ mean,
                           const float* __restrict__ stdv, u16* __restrict__ xp) {
  int idx = blockIdx.x * 256 + threadIdx.x;
  if (idx >= BSZ * NPATCHES * CH) return;
  int f = idx % CH;
  int p = (idx / CH) % NPATCHES;
  int b = idx / (CH * NPATCHES);
  int c = f >> 8;
  int py = (f >> 4) & 15;
  int px = f & 15;
  int gy = p >> 5, gx = p & 31;
  float v = x[((size_t)(b * 3 + c) * IMGSZ + gy * 16 + py) * IMGSZ + gx * 16 + px];
  xp[idx] = f2b((v * (1.0f / 255.0f) - mean[c]) / stdv[c]);
}

__global__ void k_assemble(const float* __restrict__ xpe, const float* __restrict__ prefix,
                           const float* __restrict__ pos, float* __restrict__ X) {
  int idx = blockIdx.x * 256 + threadIdx.x;
  if (idx >= BSZ * NTOK1 * CH) return;
  int c = idx % CH;
  int n = (idx / CH) % NTOK1;
  int b = idx / (CH * NTOK1);
  float v;
  if (n < NPREFIX) v = prefix[n * CH + c];
  else v = xpe[((size_t)b * NPATCHES + n - NPREFIX) * CH + c] + pos[(size_t)(n - NPREFIX) * CH + c];
  X[idx] = v;
}

__global__ void k_concat(const float* __restrict__ Xin, const float* __restrict__ qe,
                         float* __restrict__ Xout) {
  int idx = blockIdx.x * 256 + threadIdx.x;
  if (idx >= BSZ * NTOK2 * CH) return;
  int c = idx % CH;
  int n = (idx / CH) % NTOK2;
  int b = idx / (CH * NTOK2);
  float v;
  if (n < NQUERY) v = qe[n * CH + c];
  else v = Xin[((size_t)b * NTOK1 + n - NQUERY) * CH + c];
  Xout[idx] = v;
}

// repack upt_w (s, c, o, d, x) -> WPb[s][dx*768+o][c], bf16
__global__ __launch_bounds__(256) void k_repack(const float* __restrict__ upt,
                                                u16* __restrict__ WPb) {
  __shared__ float t[4][32][33];
  int o0 = blockIdx.x * 32, c0 = blockIdx.y * 32, s = blockIdx.z;
  int tid = threadIdx.x;
  for (int idx = tid; idx < 32 * 128; idx += 256) {
    int cc = idx >> 7;
    int rest = idx & 127;
    int oo = rest >> 2, dx = rest & 3;
    t[dx][oo][cc] = upt[((size_t)(s * CH + c0 + cc) * CH + o0 + oo) * 4 + dx];
  }
  __syncthreads();
  for (int idx = tid; idx < 4 * 32 * 32; idx += 256) {
    int dx = idx >> 10;
    int oo = (idx >> 5) & 31;
    int cc = idx & 31;
    WPb[((size_t)(s * 4 + dx) * CH + o0 + oo) * CH + c0 + cc] = f2b(t[dx][oo][cc]);
  }
}

// antialiased bilinear 128->32 downsample + threshold>0
__global__ void k_qmask(const float* __restrict__ mlog, unsigned char* __restrict__ qm) {
  int idx = blockIdx.x * 256 + threadIdx.x;
  if (idx >= BSZ * NQUERY * NPATCHES) return;
  int gx = idx & 31;
  int gy = (idx >> 5) & 31;
  int bq = idx >> 10;
  const float* m = mlog + (size_t)bq * 16384;
  float cy = 4.0f * gy + 1.5f, cx = 4.0f * gx + 1.5f;
  int y0 = max(0, 4 * gy - 2), y1 = min(127, 4 * gy + 5);
  int x0 = max(0, 4 * gx - 2), x1 = min(127, 4 * gx + 5);
  float num = 0.f;
  for (int jy = y0; jy <= y1; jy++) {
    float wy = 1.0f - fabsf((float)jy - cy) * 0.25f;
    float rowsum = 0.f;
    for (int jx = x0; jx <= x1; jx++) {
      float wx = 1.0f - fabsf((float)jx - cx) * 0.25f;
      rowsum = fmaf(wx, m[jy * 128 + jx], rowsum);
    }
    num = fmaf(wy, rowsum, num);
  }
  qm[idx] = (num > 0.0f) ? 1 : 0;
}

// ---------------- host orchestration ----------------
extern "C" void kernel_launch(void* const* d_in, const int* in_sizes, int n_in,
                              void* d_out_v, int out_size, void* d_ws, size_t ws_size,
                              hipStream_t stream) {
  (void)in_sizes; (void)n_in; (void)out_size; (void)ws_size;
  const float* x_in    = (const float*)d_in[0];
  const float* pmean   = (const float*)d_in[1];
  const float* pstd    = (const float*)d_in[2];
  const float* patch_w = (const float*)d_in[3];
  const float* patch_b = (const float*)d_in[4];
  const float* pos     = (const float*)d_in[5];
  const float* prefix  = (const float*)d_in[6];
  const float* qkv_w   = (const float*)d_in[7];
  const float* qkv_b   = (const float*)d_in[8];
  const float* proj_w  = (const float*)d_in[9];
  const float* proj_b  = (const float*)d_in[10];
  const float* ln1w    = (const float*)d_in[11];
  const float* ln1b    = (const float*)d_in[12];
  const float* ln2w    = (const float*)d_in[13];
  const float* ln2b    = (const float*)d_in[14];
  const float* ls1     = (const float*)d_in[15];
  const float* ls2     = (const float*)d_in[16];
  const float* fc1w    = (const float*)d_in[17];
  const float* fc1b    = (const float*)d_in[18];
  const float* fc2w    = (const float*)d_in[19];
  const float* fc2b    = (const float*)d_in[20];
  const float* normw   = (const float*)d_in[21];
  const float* normb   = (const float*)d_in[22];
  const float* qemb    = (const float*)d_in[23];
  const float* clsw    = (const float*)d_in[24];
  const float* clsb    = (const float*)d_in[25];
  const float* mh1w    = (const float*)d_in[26];
  const float* mh1b    = (const float*)d_in[27];
  const float* mh2w    = (const float*)d_in[28];
  const float* mh2b    = (const float*)d_in[29];
  const float* mh3w    = (const float*)d_in[30];
  const float* mh3b    = (const float*)d_in[31];
  const float* uptw    = (const float*)d_in[32];
  const float* uptb    = (const float*)d_in[33];
  const float* updww   = (const float*)d_in[34];
  const float* uplnw   = (const float*)d_in[35];
  const float* uplnb   = (const float*)d_in[36];

  float* out = (float*)d_out_v;
  float* out_mask = out;                                   // (5,2,100,128,128)
  float* out_cls = out + (size_t)5 * BSZ * NQUERY * 16384; // (5,2,100,151)

  char* base = (char*)d_ws;
  size_t off = 0;
  auto allocB = [&](size_t bytes) {
    void* p = base + off;
    off += (bytes + 63) & ~(size_t)63;
    return p;
  };
  // fp32
  float* Xa = (float*)allocB((size_t)BSZ * NTOK2 * CH * 4);
  float* Xb = (float*)allocB((size_t)BSZ * NTOK2 * CH * 4);
  float* Hf = (float*)allocB((size_t)BSZ * NTOK2 * CH * 4);   // XPE staging
  // bf16
  u16* Wq  = (u16*)allocB((size_t)3 * CH * CH * 2);
  u16* Wp  = (u16*)allocB((size_t)CH * CH * 2);
  u16* Wf1 = (u16*)allocB((size_t)4 * CH * CH * 2);
  u16* Wf2 = (u16*)allocB((size_t)CH * 4 * CH * 2);
  u16* Wpa = (u16*)allocB((size_t)CH * CH * 2);
  u16* Wcl = (u16*)allocB((size_t)NCLASS * CH * 2);
  u16* Wm1 = (u16*)allocB((size_t)CH * CH * 2);
  u16* Wm2 = (u16*)allocB((size_t)CH * CH * 2);
  u16* Wm3 = (u16*)allocB((size_t)CH * CH * 2);
  u16* WPb = (u16*)allocB((size_t)2 * 4 * CH * CH * 2);
  u16* LNb = (u16*)allocB((size_t)BSZ * NTOK2 * CH * 2);
  u16* AOb = (u16*)allocB((size_t)BSZ * NTOK2 * CH * 2);
  u16* XPb = (u16*)allocB((size_t)BSZ * NPATCHES * CH * 2);
  u16* HQa = (u16*)allocB((size_t)BSZ * NQUERY * CH * 2);
  u16* HQb = (u16*)allocB((size_t)BSZ * NQUERY * CH * 2);
  u16* HQc = (u16*)allocB((size_t)BSZ * NQUERY * CH * 2);
  u16* LNq = (u16*)allocB((size_t)BSZ * NQUERY * CH * 2);
  u16* LNp = (u16*)allocB((size_t)BSZ * NPATCHES * CH * 2);
  // big shared region: predict pipeline (dual batch) + layer-loop aliases
  u16* Sb  = (u16*)allocB(((size_t)4 * 4096 * CH + (size_t)4 * 16384 * CH) * 2);
  unsigned char* QM = (unsigned char*)allocB((size_t)BSZ * NQUERY * NPATCHES);

  u16* s0g  = Sb;                                   // [2][4096][768]
  u16* s0l  = Sb + (size_t)2 * 4096 * CH;           // [2][4096][768]
  u16* s1g  = Sb + (size_t)4 * 4096 * CH;           // [2][16384][768]
  u16* s1d  = s1g + (size_t)2 * 16384 * CH;         // [2][16384][768]
  u16* QKVb = Sb;                                   // rows x 2304 (layer loop)
  u16* M1b  = Sb;                                   // rows x 3072 (layer loop)

  auto bgemm = [&](const u16* A, const u16* B, const float* bias, float* Cf, u16* Cb,
                   int M, int N, int K, int lda, int ldb, int ldcf, int ldcb,
                   int flags, int lp2w, const float* lsv) {
    dim3 g((N + 127) / 128, (M + 127) / 128);
    k_bgemm<<<g, 256, 0, stream>>>(A, B, bias, Cf, Cb, M, N, K, lda, ldb, ldcf, ldcb,
                                   flags, lp2w, lsv, 0, 0, 0);
  };
  auto cvt = [&](const float* s, u16* d, int n) {
    k_cvt<<<(n / 4 + 255) / 256, 256, 0, stream>>>(s, d, n);
  };
  auto ew = [&](long tot) { return dim3((unsigned)((tot + 255) / 256)); };

  // ---- one-time weight conversions ----
  cvt(patch_w, Wpa, CH * CH);
  cvt(clsw, Wcl, NCLASS * CH);
  cvt(mh1w, Wm1, CH * CH);
  cvt(mh2w, Wm2, CH * CH);
  cvt(mh3w, Wm3, CH * CH);
  k_repack<<<dim3(24, 24, 2), 256, 0, stream>>>(uptw, WPb);

  // ---- patch embedding ----
  k_patchify<<<ew((long)BSZ * NPATCHES * CH), 256, 0, stream>>>(x_in, pmean, pstd, XPb);
  bgemm(XPb, Wpa, patch_b, Hf, nullptr, BSZ * NPATCHES, CH, CH, CH, CH, CH, 0, 0, 0, nullptr);
  k_assemble<<<ew((long)BSZ * NTOK1 * CH), 256, 0, stream>>>(Hf, prefix, pos, Xa);

  float* X = Xa;
  float* Xalt = Xb;

  auto predict = [&](float* Xcur, int pred, bool build_mask) {
    k_lnp<<<dim3(BSZ * NTOK2), 256, 0, stream>>>(Xcur, normw, normb, LNq, LNp);
    bgemm(LNq, Wcl, clsb, out_cls + (size_t)pred * BSZ * NQUERY * NCLASS, nullptr,
          BSZ * NQUERY, NCLASS, CH, CH, CH, NCLASS, 0, 0, 0, nullptr);
    bgemm(LNq, Wm1, mh1b, nullptr, HQa, BSZ * NQUERY, CH, CH, CH, CH, 0, CH, 1, 0, nullptr);
    bgemm(HQa, Wm2, mh2b, nullptr, HQb, BSZ * NQUERY, CH, CH, CH, CH, 0, CH, 1, 0, nullptr);
    bgemm(HQb, Wm3, mh3b, nullptr, HQc, BSZ * NQUERY, CH, CH, CH, CH, 0, CH, 0, 0, nullptr);
    // dual-batch upsample pipeline
    bgemm(LNp, WPb, uptb, nullptr, s0g,
          BSZ * 1024, 4 * CH, CH, CH, CH, 0, 0, 2, 5, nullptr);
    k_dwln<<<dim3(BSZ * 4096), 256, 0, stream>>>(s0g, updww, uplnw, uplnb, s0l, 64, 64);
    bgemm(s0l, WPb + (size_t)4 * CH * CH, uptb + CH, nullptr, s1g,
          BSZ * 4096, 4 * CH, CH, CH, CH, 0, 0, 2, 6, nullptr);
    k_dwln<<<dim3(BSZ * 16384), 256, 0, stream>>>(s1g, updww + CH * 9, uplnw + CH,
                                                  uplnb + CH, s1d, 128, 128);
    // mask logits: z-batched over both images (z strides select A/B/C slices)
    {
      dim3 g(16384 / 128, 1, BSZ);
      k_bgemm<<<g, 256, 0, stream>>>(
          HQc, s1d, nullptr,
          out_mask + (size_t)pred * BSZ * NQUERY * 16384, nullptr,
          NQUERY, 16384, CH, CH, CH, 16384, 0, 0, 0, nullptr,
          (long long)NQUERY * CH, (long long)16384 * CH, (long long)NQUERY * 16384);
    }
    if (build_mask) {
      k_qmask<<<ew((long)BSZ * NQUERY * NPATCHES), 256, 0, stream>>>(
          out_mask + (size_t)pred * BSZ * NQUERY * 16384, QM);
    }
  };

  int Ntok = NTOK1;
  for (int i = 0; i < LAYERS; i++) {
    if (i == LAYERS - NBLK) {
      k_concat<<<ew((long)BSZ * NTOK2 * CH), 256, 0, stream>>>(X, qemb, Xalt);
      float* t = X; X = Xalt; Xalt = t;
      Ntok = NTOK2;
    }
    if (i >= LAYERS - NBLK) predict(X, i - (LAYERS - NBLK), true);
    const int rows = BSZ * Ntok;
    // per-layer weight conversion (single dispatch)
    k_cvt_layer<<<dim3(3456), 256, 0, stream>>>(
        qkv_w + (size_t)i * 3 * CH * CH, proj_w + (size_t)i * CH * CH,
        fc1w + (size_t)i * 4 * CH * CH, fc2w + (size_t)i * CH * 4 * CH,
        Wq, Wp, Wf1, Wf2);
    // attention block
    k_ln<float><<<dim3(rows), 256, 0, stream>>>(X, ln1w + i * CH, ln1b + i * CH, LNb);
    bgemm(LNb, Wq, qkv_b + (size_t)i * 3 * CH, nullptr, QKVb,
          rows, 3 * CH, CH, CH, CH, 0, 3 * CH, 0, 0, nullptr);
    k_attn<<<dim3((Ntok + QT - 1) / QT, 12, BSZ), 256, 0, stream>>>(
        QKVb, AOb, (i >= LAYERS - NBLK) ? QM : (const unsigned char*)nullptr, Ntok);
    bgemm(AOb, Wp, proj_b + (size_t)i * CH, X, nullptr,
          rows, CH, CH, CH, CH, CH, 0, 4, 0, ls1 + i * CH);  // fused residual
    // MLP block
    k_ln<float><<<dim3(rows), 256, 0, stream>>>(X, ln2w + i * CH, ln2b + i * CH, LNb);
    bgemm(LNb, Wf1, fc1b + (size_t)i * 4 * CH, nullptr, M1b,
          rows, 4 * CH, CH, CH, CH, 0, 4 * CH, 1, 0, nullptr);
    bgemm(M1b, Wf2, fc2b + (size_t)i * CH, X, nullptr,
          rows, CH, 4 * CH, 4 * CH, 4 * CH, CH, 0, 4, 0, ls2 + i * CH);  // fused residual
  }
  predict(X, 4, false);
}